// Round 1
// baseline (123.536 us; speedup 1.0000x reference)
//
#include <hip/hip_runtime.h>
#include <hip/hip_bf16.h>

// BiClassifier: B=4, N1=N2=128, D=768, HID=1024, OUT=2
// Kernel 1: hid[1024][1024]: rows 0..511  = input1@W1.T + b1  (flat [B*N1][HID])
//                            rows 512..1023 = input2@W2.T      (flat [B*N2][HID])
// Kernel 2: out[b,n,m,o] = sum_h relu(hid[bn][h] + hid[512+bm][h]) * Wo[o][h] + bo[o]

#define KC 16

__global__ __launch_bounds__(256) void gemm_in(
    const float* __restrict__ in1, const float* __restrict__ in2,
    const float* __restrict__ W1, const float* __restrict__ b1,
    const float* __restrict__ W2, float* __restrict__ hid)
{
    const int t    = threadIdx.x;
    const int row0 = blockIdx.y * 64;
    const int col0 = blockIdx.x * 64;
    const bool first = (row0 < 512);
    const float* __restrict__ A = first ? (in1 + (size_t)row0 * 768)
                                        : (in2 + (size_t)(row0 - 512) * 768);
    const float* __restrict__ W = first ? W1 : W2;

    // +4 pad: staging transpose-writes and fragment reads stay <=2-way (free)
    __shared__ float As[KC][68];
    __shared__ float Ws[KC][68];

    // staging mapping: thread t loads A[lr][k+lc..+3], W[col0+lr][k+lc..+3]
    const int lr = t >> 2;          // 0..63
    const int lc = (t & 3) << 2;    // 0,4,8,12
    const float* Aptr = A + (size_t)lr * 768 + lc;
    const float* Wptr = W + (size_t)(col0 + lr) * 768 + lc;

    // compute mapping: wave = 4 row-groups x 16 col-groups -> A reads broadcast
    const int tx = t & 15;          // col group (4 cols each)
    const int ty = t >> 4;          // row group (4 rows each)

    float4 ar = *(const float4*)Aptr;
    float4 wr = *(const float4*)Wptr;

    float acc[4][4] = {};

    for (int kt = 0; kt < 768 / KC; ++kt) {
        __syncthreads();
        // transpose-write prefetched regs into LDS: As[kk][row]
        As[lc + 0][lr] = ar.x; As[lc + 1][lr] = ar.y;
        As[lc + 2][lr] = ar.z; As[lc + 3][lr] = ar.w;
        Ws[lc + 0][lr] = wr.x; Ws[lc + 1][lr] = wr.y;
        Ws[lc + 2][lr] = wr.z; Ws[lc + 3][lr] = wr.w;
        __syncthreads();
        if (kt < 768 / KC - 1) {
            ar = *(const float4*)(Aptr + (size_t)(kt + 1) * KC);
            wr = *(const float4*)(Wptr + (size_t)(kt + 1) * KC);
        }
        #pragma unroll
        for (int kk = 0; kk < KC; ++kk) {
            const float4 av = *(const float4*)&As[kk][ty << 2];
            const float4 wv = *(const float4*)&Ws[kk][tx << 2];
            acc[0][0] = fmaf(av.x, wv.x, acc[0][0]);
            acc[0][1] = fmaf(av.x, wv.y, acc[0][1]);
            acc[0][2] = fmaf(av.x, wv.z, acc[0][2]);
            acc[0][3] = fmaf(av.x, wv.w, acc[0][3]);
            acc[1][0] = fmaf(av.y, wv.x, acc[1][0]);
            acc[1][1] = fmaf(av.y, wv.y, acc[1][1]);
            acc[1][2] = fmaf(av.y, wv.z, acc[1][2]);
            acc[1][3] = fmaf(av.y, wv.w, acc[1][3]);
            acc[2][0] = fmaf(av.z, wv.x, acc[2][0]);
            acc[2][1] = fmaf(av.z, wv.y, acc[2][1]);
            acc[2][2] = fmaf(av.z, wv.z, acc[2][2]);
            acc[2][3] = fmaf(av.z, wv.w, acc[2][3]);
            acc[3][0] = fmaf(av.w, wv.x, acc[3][0]);
            acc[3][1] = fmaf(av.w, wv.y, acc[3][1]);
            acc[3][2] = fmaf(av.w, wv.z, acc[3][2]);
            acc[3][3] = fmaf(av.w, wv.w, acc[3][3]);
        }
    }

    float4 bias = make_float4(0.f, 0.f, 0.f, 0.f);
    if (first) bias = *(const float4*)&b1[col0 + (tx << 2)];
    const size_t obase = (size_t)(row0 + (ty << 2)) * 1024 + col0 + (tx << 2);
    #pragma unroll
    for (int i = 0; i < 4; ++i) {
        float4 o;
        o.x = acc[i][0] + bias.x;
        o.y = acc[i][1] + bias.y;
        o.z = acc[i][2] + bias.z;
        o.w = acc[i][3] + bias.w;
        *(float4*)&hid[obase + (size_t)i * 1024] = o;
    }
}

#define HC 128

__global__ __launch_bounds__(256) void pair_kernel(
    const float* __restrict__ hid, const float* __restrict__ Wo,
    const float* __restrict__ bo, float* __restrict__ out)
{
    const int t  = threadIdx.x;
    const int b  = blockIdx.z;
    const int n0 = blockIdx.y * 16;
    const int m0 = blockIdx.x * 16;
    const float* __restrict__ in1 = hid + ((size_t)b * 128 + n0) * 1024;
    const float* __restrict__ in2 = hid + (size_t)512 * 1024 + ((size_t)b * 128 + m0) * 1024;

    __shared__ float s1[16][132];   // pad 132: 16-row reads -> 2-way (free)
    __shared__ float s2[16][132];
    __shared__ float sw0[HC];
    __shared__ float sw1[HC];

    // staging: 16 rows x 128 floats per tensor per chunk; thread loads rows sr, sr+8
    const int sr = t >> 5;          // 0..7
    const int sc = (t & 31) << 2;   // 0..124

    float4 a0 = *(const float4*)(in1 + (size_t)sr * 1024 + sc);
    float4 a1 = *(const float4*)(in1 + (size_t)(sr + 8) * 1024 + sc);
    float4 c0 = *(const float4*)(in2 + (size_t)sr * 1024 + sc);
    float4 c1 = *(const float4*)(in2 + (size_t)(sr + 8) * 1024 + sc);
    float4 wv = make_float4(0.f, 0.f, 0.f, 0.f);
    if (t < 64) wv = *(const float4*)(Wo + (size_t)(t >> 5) * 1024 + ((t & 31) << 2));

    const int i = t >> 4;           // n index within tile
    const int j = t & 15;           // m index within tile
    float acc0 = 0.f, acc1 = 0.f;

    for (int hc = 0; hc < 1024 / HC; ++hc) {
        __syncthreads();
        *(float4*)&s1[sr][sc] = a0;
        *(float4*)&s1[sr + 8][sc] = a1;
        *(float4*)&s2[sr][sc] = c0;
        *(float4*)&s2[sr + 8][sc] = c1;
        if (t < 64) {
            if (t < 32) *(float4*)&sw0[(t & 31) << 2] = wv;
            else        *(float4*)&sw1[(t & 31) << 2] = wv;
        }
        __syncthreads();
        if (hc < 1024 / HC - 1) {
            const int off = (hc + 1) * HC;
            a0 = *(const float4*)(in1 + (size_t)sr * 1024 + off + sc);
            a1 = *(const float4*)(in1 + (size_t)(sr + 8) * 1024 + off + sc);
            c0 = *(const float4*)(in2 + (size_t)sr * 1024 + off + sc);
            c1 = *(const float4*)(in2 + (size_t)(sr + 8) * 1024 + off + sc);
            if (t < 64) wv = *(const float4*)(Wo + (size_t)(t >> 5) * 1024 + off + ((t & 31) << 2));
        }
        #pragma unroll
        for (int hh = 0; hh < HC; hh += 4) {
            const float4 x = *(const float4*)&s1[i][hh];
            const float4 y = *(const float4*)&s2[j][hh];
            const float4 u = *(const float4*)&sw0[hh];
            const float4 v = *(const float4*)&sw1[hh];
            float r;
            r = fmaxf(x.x + y.x, 0.f); acc0 = fmaf(r, u.x, acc0); acc1 = fmaf(r, v.x, acc1);
            r = fmaxf(x.y + y.y, 0.f); acc0 = fmaf(r, u.y, acc0); acc1 = fmaf(r, v.y, acc1);
            r = fmaxf(x.z + y.z, 0.f); acc0 = fmaf(r, u.z, acc0); acc1 = fmaf(r, v.z, acc1);
            r = fmaxf(x.w + y.w, 0.f); acc0 = fmaf(r, u.w, acc0); acc1 = fmaf(r, v.w, acc1);
        }
    }

    const float2 ob = *(const float2*)bo;
    const size_t o = (((size_t)b * 128 + n0 + i) * 128 + (m0 + j)) * 2;
    out[o]     = acc0 + ob.x;
    out[o + 1] = acc1 + ob.y;
}

extern "C" void kernel_launch(void* const* d_in, const int* in_sizes, int n_in,
                              void* d_out, int out_size, void* d_ws, size_t ws_size,
                              hipStream_t stream) {
    (void)in_sizes; (void)n_in; (void)out_size; (void)ws_size;
    const float* input1 = (const float*)d_in[0];
    const float* input2 = (const float*)d_in[1];
    const float* W1     = (const float*)d_in[2];
    const float* b1     = (const float*)d_in[3];
    const float* W2     = (const float*)d_in[4];
    const float* Wo     = (const float*)d_in[5];
    const float* bo     = (const float*)d_in[6];
    float* out = (float*)d_out;
    float* hid = (float*)d_ws;   // 1024*1024 floats = 4 MB

    dim3 blk(256);
    gemm_in<<<dim3(16, 16), blk, 0, stream>>>(input1, input2, W1, b1, W2, hid);
    pair_kernel<<<dim3(8, 8, 4), blk, 0, stream>>>(hid, Wo, bo, out);
}